// Round 7
// baseline (276.605 us; speedup 1.0000x reference)
//
#include <hip/hip_runtime.h>
#include <math.h>

// ---------------- problem constants ----------------
#define NIMG   8
#define NA     15
#define GH     100
#define GW     100
#define HW     10000
#define HWA    150000      // NA*HW
#define NF4    37500       // HWA/4
#define PRE    2000
#define POST   1000
#define CAP    4096        // candidate cap; logit-binning keeps C ~2030
#define NBINS  2048
#define MROWS  2048        // mask rows per image (padded past PRE)
#define BBOX_CLIP_F 4.135166556742356f
#define IMGSZ  1600.0f
#define BINSCALE 170.6666667f   // NBINS / 12 over logit range [-6,6]

// ---------------- workspace layout (bytes) ----------------
#define WS_TOPB   0u            // f32 [8][2000][4]   256000
#define WS_TOPS   256000u       // f32 [8][2000]      64000 -> 320000 (+256 pad)
#define WS_MASK   320256u       // u64 [8][2048][32]  4194304 -> 4514560
// no memset needed: every consumed byte is written by a producer kernel
// (mask rows >= PRE are never kept/folded: vbit requires i < PRE)

// s_waitcnt imm: vmcnt[3:0]+[15:14], expcnt[6:4]=7 (ignore), lgkmcnt[11:8]=15 (ignore)
#define WAIT_VM(n) __builtin_amdgcn_s_waitcnt(((n)&15)|(((n)>>4)<<14)|0xF70)
#define WAIT_LGKM0 __builtin_amdgcn_s_waitcnt(0xC07F)   // lgkmcnt(0), vmcnt=63

// async global->LDS DMA, 16 B/lane, zero VGPR results (compiler can't serialize it)
__device__ __forceinline__ void gl_lds16(const void* g, void* l) {
    __builtin_amdgcn_global_load_lds(
        (const __attribute__((address_space(1))) unsigned int*)g,
        (__attribute__((address_space(3))) unsigned int*)l, 16, 0, 0);
}

// Correctly-rounded f32 exp via double, feeding an IEEE f32 add/div chain.
// Models CPU-reference sigmoid. VERIFIED bit-exact R1-R6.
__device__ __forceinline__ float ref_exp_f32(float x) {
    return (float)exp((double)x);
}
__device__ __forceinline__ float ref_sigmoid(float x) {
    float t = ref_exp_f32(-x);
    return __fdiv_rn(1.0f, __fadd_rn(1.0f, t));
}

// monotone logit->bin map (identical in hist and compact phases)
__device__ __forceinline__ int logit_bin(float x) {
    int b = (int)floorf(__fmul_rn(__fadd_rn(x, 6.0f), BINSCALE));
    return max(0, min(NBINS - 1, b));
}

// 64-bit wave-uniform broadcast via scalar readlane
__device__ __forceinline__ unsigned long long rl64(unsigned long long v, int l) {
    unsigned lo = (unsigned)__builtin_amdgcn_readlane((int)(unsigned)v, l);
    unsigned hi = (unsigned)__builtin_amdgcn_readlane((int)(unsigned)(v >> 32), l);
    return ((unsigned long long)hi << 32) | (unsigned long long)lo;
}

// ---- K1: fused hist + b* + compact + bitonic sort + decode (1 block/image) ----
// All intermediates live in LDS; obj 2nd pass hits this XCD's L2.
__global__ void __launch_bounds__(1024) k_prep(
        const float* __restrict__ obj,
        const float* __restrict__ deltas,
        float* __restrict__ topb,
        float* __restrict__ tops) {
    __shared__ unsigned shist[NBINS];              // 8 KB
    __shared__ unsigned long long sk[CAP];         // 32 KB (compact buffer == sort buffer)
    __shared__ unsigned lcnt_sh;
    __shared__ int bs_sh;
    const int n = blockIdx.x, tid = threadIdx.x;
    const float4* op4 = (const float4*)(obj + (size_t)n * HWA);   // NF4 float4s

    for (int t = tid; t < NBINS; t += 1024) shist[t] = 0u;
    for (int t = tid; t < CAP; t += 1024) sk[t] = 0ull;
    if (tid == 0) lcnt_sh = 0u;
    __syncthreads();

    // pass 1: histogram (vectorized loads, LDS atomics)
    for (int t = tid; t < NF4; t += 1024) {
        float4 v = op4[t];
        atomicAdd(&shist[logit_bin(v.x)], 1u);
        atomicAdd(&shist[logit_bin(v.y)], 1u);
        atomicAdd(&shist[logit_bin(v.z)], 1u);
        atomicAdd(&shist[logit_bin(v.w)], 1u);
    }
    __syncthreads();

    // wave 0: b* = max{b : sum_{x>=b} hist[x] >= PRE}  (0 if total < PRE)
    if (tid < 64) {
        const int lane = tid;
        unsigned v[32]; unsigned S = 0;
        #pragma unroll
        for (int t = 0; t < 32; ++t) { v[t] = shist[lane * 32 + t]; S += v[t]; }
        unsigned T = S;
        #pragma unroll
        for (int d = 1; d < 64; d <<= 1) {
            unsigned u = __shfl_down(T, d);
            if (lane + d < 64) T += u;
        }
        unsigned Tn = T - S;
        int bestt = -1; unsigned W = 0;
        #pragma unroll
        for (int t = 31; t >= 0; --t) {
            W += v[t];
            if (bestt < 0 && W + Tn >= PRE) bestt = t;
        }
        unsigned long long hm = __ballot(bestt >= 0);
        int bs = 0;
        if (hm != 0ull) {
            int hl = 63 - __builtin_clzll(hm);
            int bt = __builtin_amdgcn_readlane(bestt, hl);
            bs = hl * 32 + bt;
        }
        if (lane == 0) bs_sh = bs;
    }
    __syncthreads();
    const int bs = bs_sh;

    // pass 2: compact candidates straight into the sort buffer
    // key = (score_bits << 32) | (0xFFFFFFFF - j) -> desc = score desc, index asc
    for (int t = tid; t < NF4; t += 1024) {
        float4 v = op4[t];
        float xs[4] = {v.x, v.y, v.z, v.w};
        #pragma unroll
        for (int k = 0; k < 4; ++k) {
            float x = xs[k];
            if (logit_bin(x) >= bs) {
                int e = t * 4 + k;                 // obj layout: e = a*HW + hw
                unsigned sb = __float_as_uint(ref_sigmoid(x));
                unsigned j = (unsigned)((e % HW) * NA + e / HW);
                unsigned p = atomicAdd(&lcnt_sh, 1u);
                if (p < CAP)
                    sk[p] = ((unsigned long long)sb << 32) |
                            (unsigned long long)(0xFFFFFFFFu - j);
            }
        }
    }
    __syncthreads();
    const int C = (int)((lcnt_sh < CAP) ? lcnt_sh : CAP);
    const int NEL = (C <= 2048) ? 2048 : CAP;      // slots >= C are zero

    // bitonic sort (desc) on NEL elements
    for (int k = 2; k <= NEL; k <<= 1) {
        for (int j = k >> 1; j > 0; j >>= 1) {
            for (int p = tid; p < (NEL >> 1); p += 1024) {
                int t = ((p & ~(j - 1)) << 1) | (p & (j - 1));
                int ixj = t | j;
                unsigned long long a = sk[t], b = sk[ixj];
                bool up = (t & k) == 0;
                if (up ? (a < b) : (a > b)) { sk[t] = b; sk[ixj] = a; }
            }
            __syncthreads();
        }
    }

    // decode top PRE (C >= PRE guaranteed by cutoff choice)
    const float* dp = deltas + (size_t)n * (NA * 4 * HW);
    for (int t = tid; t < PRE; t += 1024) {
        unsigned long long key = sk[t];
        unsigned sb = (unsigned)(key >> 32);
        unsigned j  = 0xFFFFFFFFu - (unsigned)(key & 0xFFFFFFFFull);
        float s = __uint_as_float(sb);
        int a  = (int)(j % NA), hw = (int)(j / NA);
        int gy = hw / GW, gx = hw % GW;
        int r  = a / 5, si = a % 5;
        // cell anchor, bit-exact vs reference f32 math
        float ratio = (r == 0) ? 0.5f : ((r == 1) ? 1.0f : 2.0f);
        float hr = __fsqrt_rn(ratio);
        float wr = __fdiv_rn(1.0f, hr);
        float scale = (float)(32 << si);
        float wsz = __fmul_rn(wr, scale);
        float hsz = __fmul_rn(hr, scale);
        float bx1 = rintf(__fmul_rn(-wsz, 0.5f));
        float by1 = rintf(__fmul_rn(-hsz, 0.5f));
        float bx2 = rintf(__fmul_rn(wsz, 0.5f));
        float by2 = rintf(__fmul_rn(hsz, 0.5f));
        float sx = (float)(gx * 16), sy = (float)(gy * 16);
        float ax1 = sx + bx1, ay1 = sy + by1, ax2 = sx + bx2, ay2 = sy + by2;
        float wa = __fsub_rn(ax2, ax1), ha = __fsub_rn(ay2, ay1);
        float cxa = __fadd_rn(ax1, __fmul_rn(0.5f, wa));
        float cya = __fadd_rn(ay1, __fmul_rn(0.5f, ha));
        int off = gy * GW + gx;
        float dx = dp[(a * 4 + 0) * HW + off];
        float dy = dp[(a * 4 + 1) * HW + off];
        float dw = fminf(dp[(a * 4 + 2) * HW + off], BBOX_CLIP_F);
        float dh = fminf(dp[(a * 4 + 3) * HW + off], BBOX_CLIP_F);
        float cx = __fadd_rn(__fmul_rn(dx, wa), cxa);
        float cy = __fadd_rn(__fmul_rn(dy, ha), cya);
        float bw = __fmul_rn(ref_exp_f32(dw), wa);
        float bh = __fmul_rn(ref_exp_f32(dh), ha);
        float hbw = __fmul_rn(0.5f, bw), hbh = __fmul_rn(0.5f, bh);
        float x1 = fminf(fmaxf(__fsub_rn(cx, hbw), 0.0f), IMGSZ);
        float y1 = fminf(fmaxf(__fsub_rn(cy, hbh), 0.0f), IMGSZ);
        float x2 = fminf(fmaxf(__fadd_rn(cx, hbw), 0.0f), IMGSZ);
        float y2 = fminf(fmaxf(__fadd_rn(cy, hbh), 0.0f), IMGSZ);
        float* tb = topb + ((size_t)n * PRE + t) * 4;
        tb[0] = x1; tb[1] = y1; tb[2] = x2; tb[3] = y2;
        bool valid = (__fsub_rn(x2, x1) >= 1e-3f) && (__fsub_rn(y2, y1) >= 1e-3f);
        tops[(size_t)n * PRE + t] = valid ? s : -1.0f;
    }
}

// ---- K2: 2000x2000 IoU suppression bitmask (bit j of row i: j>i && iou>0.7) ----
// chunks c < i>>6 are all-zero by j>i -> start there (stored 0), ~1.9x less work.
// grid (NIMG, 63): all of image n's blocks land on XCD n -> mask stays in that L2
__global__ void k_iou(const float* __restrict__ topb,
                      unsigned long long* __restrict__ mask) {
    __shared__ float X1[PRE], Y1[PRE], X2[PRE], Y2[PRE];
    const int n = blockIdx.x, rowblk = blockIdx.y, tid = threadIdx.x;
    const float4* tb4 = (const float4*)(topb + (size_t)n * PRE * 4);
    for (int t = tid; t < PRE; t += 256) {
        float4 b = tb4[t];
        X1[t] = b.x; Y1[t] = b.y; X2[t] = b.z; Y2[t] = b.w;
    }
    __syncthreads();
    const int wave = tid >> 6, lane = tid & 63;
    for (int rr = 0; rr < 8; ++rr) {
        int i = rowblk * 32 + wave * 8 + rr;
        if (i >= PRE) break;
        float bi0 = X1[i], bi1 = Y1[i], bi2 = X2[i], bi3 = Y2[i];
        float ai = __fmul_rn(__fsub_rn(bi2, bi0), __fsub_rn(bi3, bi1));
        unsigned long long* mrow = mask + ((size_t)n * MROWS + i) * 32;
        unsigned long long mval = 0ull;     // lane c<32 collects chunk c
        const int c0 = i >> 6;
        for (int c = c0; c < 32; ++c) {
            int j = c * 64 + lane;
            bool bit = false;
            if (j < PRE && j > i) {
                float bj0 = X1[j], bj1 = Y1[j], bj2 = X2[j], bj3 = Y2[j];
                float aj = __fmul_rn(__fsub_rn(bj2, bj0), __fsub_rn(bj3, bj1));
                float ltx = fmaxf(bi0, bj0), lty = fmaxf(bi1, bj1);
                float rbx = fminf(bi2, bj2), rby = fminf(bi3, bj3);
                float ww = fmaxf(__fsub_rn(rbx, ltx), 0.0f);
                float hh = fmaxf(__fsub_rn(rby, lty), 0.0f);
                float inter = __fmul_rn(ww, hh);
                float denom = __fadd_rn(__fsub_rn(__fadd_rn(ai, aj), inter), 1e-6f);
                bit = __fdiv_rn(inter, denom) > 0.7f;
            }
            unsigned long long m = __ballot(bit);
            if (lane == c) mval = m;
        }
        if (lane < 32) mrow[lane] = mval;   // one coalesced 256B store per row
    }
}

// ---- K3: greedy NMS. Pure-scalar decision chain; rr from the staged LDS buffer
// (no per-group global loads); parallel kept-emission; DMA two groups ahead.
__global__ void __launch_bounds__(256) k_nms_out(
        const float* __restrict__ topb,
        const float* __restrict__ tops,
        const unsigned long long* __restrict__ mask,
        float* __restrict__ out) {
    __shared__ unsigned long long sbuf[2][2048];   // 2 x 16 KB staging (64 rows each)
    __shared__ float sval[2048];                   // scores (8 KB)
    __shared__ unsigned short kept[POST];
    __shared__ int cnt;
    const int n = blockIdx.x, tid = threadIdx.x;   // 256 threads; wave 0 does NMS
    const float* sp = tops + (size_t)n * PRE;
    if (tid < 64) {
        const int lane = tid;
        const unsigned long long* mb = mask + (size_t)n * MROWS * 32;
        // stage scores via DMA (reads 192 B past tops[n] slice: inside ws pad)
        #pragma unroll
        for (int k = 0; k < 8; ++k)
            gl_lds16((const char*)sp + k * 1024 + lane * 16, (char*)sval + k * 1024);
        WAIT_VM(0);
        unsigned long long vbit = 0ull;   // lane w<32: validity of rows [64w,64w+64)
        #pragma unroll
        for (int w = 0; w < 32; ++w) {
            int i = w * 64 + lane;
            bool v = (i < PRE) && (sval[i] > -0.5f);
            unsigned long long m = __ballot(v);
            if (lane == w) vbit = m;
        }
        // prologue: stage groups 0 and 1
        #pragma unroll
        for (int k = 0; k < 16; ++k)
            gl_lds16((const char*)mb + k * 1024 + lane * 16,
                     (char*)&sbuf[0][0] + k * 1024);
        #pragma unroll
        for (int k = 0; k < 16; ++k)
            gl_lds16((const char*)(mb + (size_t)64 * 32) + k * 1024 + lane * 16,
                     (char*)&sbuf[1][0] + k * 1024);

        unsigned long long remv = 0ull;   // lane l owns suppression chunk (l&31)
        int kc = 0;
        for (int g = 0; g < 32; ++g) {
            const int base = g * 64;
            WAIT_VM(16);                   // stage(g) done; stage(g+1) may fly
            const unsigned long long* sb = sbuf[g & 1];
            // row (base+lane)'s chunk g (bank-aliased read, once per group)
            unsigned long long rr = sb[(size_t)lane * 32 + g];
            unsigned long long cc = rl64(remv, g);
            unsigned long long vb = rl64(vbit, g);
            // pure scalar greedy chain (no POST check: surplus kept are harmless,
            // reference also computes full keep then takes first POST)
            unsigned long long todo = vb & ~cc;
            unsigned long long kb = 0ull;
            while (todo) {
                int jj = (int)__builtin_ctzll(todo);
                unsigned long long bit = 1ull << jj;
                kb |= bit;
                unsigned long long sup = rl64(rr, jj);
                todo &= ~(sup | bit);
            }
            // parallel emission: rank by popcount-below
            if (kb) {
                if ((kb >> lane) & 1ull) {
                    int rank = __popcll(kb & ((1ull << lane) - 1ull));
                    int pos = kc + rank;
                    if (pos < POST) kept[pos] = (unsigned short)(base + lane);
                }
                kc += __popcll(kb);
            }
            if (kc >= POST || g == 31) break;   // future groups irrelevant
            // fold kept rows' full masks into remv (off the decision chain)
            if (kb) {
                int h = lane >> 5, c = lane & 31;
                unsigned kbl = (unsigned)(h ? (kb >> 32) : kb);
                unsigned long long acc = 0ull;
                #pragma unroll
                for (int q = 0; q < 32; ++q) {
                    unsigned long long v = sb[(h * 32 + q) * 32 + c];
                    acc |= ((kbl >> q) & 1u) ? v : 0ull;
                }
                acc |= __shfl(acc, lane ^ 32);   // merge row-halves
                remv |= acc;
            }
            WAIT_LGKM0;                      // LDS reads done before DMA overwrites
            if (g + 2 < 32) {                // stage(g+2) into same-parity buffer
                const char* gb = (const char*)(mb + (size_t)(g + 2) * 64 * 32);
                char* lb = (char*)&sbuf[g & 1][0];
                #pragma unroll
                for (int k = 0; k < 16; ++k)
                    gl_lds16(gb + k * 1024 + lane * 16, lb + k * 1024);
            }
        }
        if (lane == 0) cnt = (kc < POST) ? kc : POST;
    }
    __syncthreads();
    const int kc = cnt;
    for (int rI = tid; rI < POST; rI += 256) {
        float o0 = 0.f, o1 = 0.f, o2 = 0.f, o3 = 0.f, o4 = 0.f;
        if (rI < kc) {
            int i = kept[rI];
            const float* tb = topb + ((size_t)n * PRE + i) * 4;
            o0 = tb[0]; o1 = tb[1]; o2 = tb[2]; o3 = tb[3]; o4 = sval[i];
        }
        float* op = out + ((size_t)n * POST + rI) * 5;
        op[0] = o0; op[1] = o1; op[2] = o2; op[3] = o3; op[4] = o4;
    }
}

extern "C" void kernel_launch(void* const* d_in, const int* in_sizes, int n_in,
                              void* d_out, int out_size, void* d_ws, size_t ws_size,
                              hipStream_t stream) {
    const float* obj    = (const float*)d_in[0];   // [8,15,100,100]
    const float* deltas = (const float*)d_in[1];   // [8,60,100,100]
    float* out = (float*)d_out;                    // [8,1000,5]
    char* ws = (char*)d_ws;

    float*               topb  = (float*)(ws + WS_TOPB);
    float*               tops  = (float*)(ws + WS_TOPS);
    unsigned long long*  mask  = (unsigned long long*)(ws + WS_MASK);

    k_prep   <<<NIMG, 1024, 0, stream>>>(obj, deltas, topb, tops);
    k_iou    <<<dim3(NIMG, 63), 256, 0, stream>>>(topb, mask);
    k_nms_out<<<NIMG, 256, 0, stream>>>(topb, tops, mask, out);
}

// Round 8
// 225.716 us; speedup vs baseline: 1.2255x; 1.2255x over previous
//
#include <hip/hip_runtime.h>
#include <math.h>

// ---------------- problem constants ----------------
#define NIMG   8
#define NA     15
#define GH     100
#define GW     100
#define HW     10000
#define HWA    150000      // NA*HW
#define NSLICE 12
#define F4S    3125        // float4s per slice (NSLICE*F4S*4 == HWA)
#define PRE    2000
#define POST   1000
#define CAP    4096        // candidate cap; logit-binning keeps C ~2030
#define NBINS  2048
#define MROWS  2048        // mask rows per image (padded past PRE)
#define LBUF   2048        // per-block LDS candidate buffer (mean ~170, 12x slack)
#define BBOX_CLIP_F 4.135166556742356f
#define IMGSZ  1600.0f
#define BINSCALE 170.6666667f   // NBINS / 12 over logit range [-6,6]

// ---------------- workspace layout (bytes) ----------------
#define WS_CNT    0u            // u32 [8]               32  (zeroed by k_hist)
#define WS_CAND   64u           // u64 [8][4096]         262144 -> 262208
#define WS_PHIST  262208u       // u32 [8][12][2048]     786432 -> 1048640
#define WS_TOPB   1048640u      // f32 [8][2000][4]      256000 -> 1304640
#define WS_TOPS   1304640u      // f32 [8][2000]         64000  -> 1368640 (+256 pad)
#define WS_MASK   1368896u      // u64 [8][2048][32]     4194304 -> 5563200
// no memset launch: cnt zeroed by k_hist; sk zero-padded in k_sort_decode;
// mask rows >= PRE never influence NMS (vbit requires i < PRE)

// s_waitcnt imm: vmcnt[3:0]+[15:14], expcnt[6:4]=7 (ignore), lgkmcnt[11:8]=15 (ignore)
#define WAIT_VM(n) __builtin_amdgcn_s_waitcnt(((n)&15)|(((n)>>4)<<14)|0xF70)
#define WAIT_LGKM0 __builtin_amdgcn_s_waitcnt(0xC07F)   // lgkmcnt(0), vmcnt=63

// async global->LDS DMA, 16 B/lane, zero VGPR results (compiler can't serialize it)
__device__ __forceinline__ void gl_lds16(const void* g, void* l) {
    __builtin_amdgcn_global_load_lds(
        (const __attribute__((address_space(1))) unsigned int*)g,
        (__attribute__((address_space(3))) unsigned int*)l, 16, 0, 0);
}

// Correctly-rounded f32 exp via double, feeding an IEEE f32 add/div chain.
// Models CPU-reference sigmoid. VERIFIED bit-exact R1-R7.
__device__ __forceinline__ float ref_exp_f32(float x) {
    return (float)exp((double)x);
}
__device__ __forceinline__ float ref_sigmoid(float x) {
    float t = ref_exp_f32(-x);
    return __fdiv_rn(1.0f, __fadd_rn(1.0f, t));
}

// monotone logit->bin map (identical in k_hist and k_compact)
__device__ __forceinline__ int logit_bin(float x) {
    int b = (int)floorf(__fmul_rn(__fadd_rn(x, 6.0f), BINSCALE));
    return max(0, min(NBINS - 1, b));
}

// 64-bit wave-uniform broadcast via scalar readlane
__device__ __forceinline__ unsigned long long rl64(unsigned long long v, int l) {
    unsigned lo = (unsigned)__builtin_amdgcn_readlane((int)(unsigned)v, l);
    unsigned hi = (unsigned)__builtin_amdgcn_readlane((int)(unsigned)(v >> 32), l);
    return ((unsigned long long)hi << 32) | (unsigned long long)lo;
}

// ---- K1: logit histogram -> per-(image,slice) PARTIAL hist (float4 loads) ----
// grid (NIMG, NSLICE): linear id = n + NIMG*slice -> image n pinned per XCD
__global__ void __launch_bounds__(1024) k_hist(
        const float* __restrict__ obj,
        unsigned* __restrict__ phist,
        unsigned* __restrict__ cnt) {
    __shared__ unsigned lh[NBINS];
    const int n = blockIdx.x, slice = blockIdx.y, tid = threadIdx.x;
    if (slice == 0 && tid == 0) cnt[n] = 0u;   // replaces memset launch
    for (int t = tid; t < NBINS; t += 1024) lh[t] = 0u;
    __syncthreads();
    const float4* op4 = (const float4*)(obj + (size_t)n * HWA) + (size_t)slice * F4S;
    for (int t = tid; t < F4S; t += 1024) {
        float4 v = op4[t];
        atomicAdd(&lh[logit_bin(v.x)], 1u);
        atomicAdd(&lh[logit_bin(v.y)], 1u);
        atomicAdd(&lh[logit_bin(v.z)], 1u);
        atomicAdd(&lh[logit_bin(v.w)], 1u);
    }
    __syncthreads();
    unsigned* ph = phist + ((size_t)n * NSLICE + slice) * NBINS;
    for (int t = tid; t < NBINS; t += 1024) ph[t] = lh[t];   // plain stores
}

// ---- K2: sum partials, b* in-block, compact via LDS staging (float4 loads) ----
// ONE global atomic per block (range reservation) instead of one per candidate.
__global__ void __launch_bounds__(1024) k_compact(
        const float* __restrict__ obj,
        const unsigned* __restrict__ phist,
        unsigned long long* __restrict__ cand,
        unsigned* __restrict__ cnt) {
    __shared__ unsigned shist[NBINS];              // 8 KB
    __shared__ unsigned long long lbuf[LBUF];      // 16 KB candidate staging
    __shared__ unsigned lcnt_sh, gbase_sh;
    __shared__ int bs_sh;
    const int n = blockIdx.x, slice = blockIdx.y, tid = threadIdx.x;
    // phase 1: sum the NSLICE partial histograms (independent loads)
    const unsigned* ph = phist + (size_t)n * NSLICE * NBINS;
    for (int b = tid; b < NBINS; b += 1024) {
        unsigned s = 0;
        #pragma unroll
        for (int k = 0; k < NSLICE; ++k) s += ph[k * NBINS + b];
        shist[b] = s;
    }
    if (tid == 0) lcnt_sh = 0u;
    __syncthreads();
    // phase 2: wave 0 computes b* = max{b : sum_{x>=b} hist[x] >= PRE}
    if (tid < 64) {
        const int lane = tid;
        unsigned v[32]; unsigned S = 0;
        #pragma unroll
        for (int t = 0; t < 32; ++t) { v[t] = shist[lane * 32 + t]; S += v[t]; }
        unsigned T = S;
        #pragma unroll
        for (int d = 1; d < 64; d <<= 1) {
            unsigned u = __shfl_down(T, d);
            if (lane + d < 64) T += u;
        }
        unsigned Tn = T - S;
        int bestt = -1; unsigned W = 0;
        #pragma unroll
        for (int t = 31; t >= 0; --t) {
            W += v[t];
            if (bestt < 0 && W + Tn >= PRE) bestt = t;
        }
        unsigned long long hm = __ballot(bestt >= 0);
        int bs = 0;
        if (hm != 0ull) {
            int hl = 63 - __builtin_clzll(hm);
            int bt = __builtin_amdgcn_readlane(bestt, hl);
            bs = hl * 32 + bt;
        }
        if (lane == 0) bs_sh = bs;
    }
    __syncthreads();
    // phase 3: scan slice (float4), stage candidates in LDS (shared atomics only)
    const int bs = bs_sh;
    const float4* op4 = (const float4*)(obj + (size_t)n * HWA) + (size_t)slice * F4S;
    const int ebase = slice * (F4S * 4);
    unsigned long long* cp = cand + (size_t)n * CAP;
    for (int t = tid; t < F4S; t += 1024) {
        float4 v = op4[t];
        float xs[4] = {v.x, v.y, v.z, v.w};
        #pragma unroll
        for (int k = 0; k < 4; ++k) {
            float x = xs[k];
            if (logit_bin(x) >= bs) {
                int e = ebase + t * 4 + k;        // obj layout: e = a*HW + hw
                unsigned sb = __float_as_uint(ref_sigmoid(x));
                unsigned j = (unsigned)((e % HW) * NA + e / HW);
                unsigned long long key = ((unsigned long long)sb << 32) |
                                         (unsigned long long)(0xFFFFFFFFu - j);
                unsigned p = atomicAdd(&lcnt_sh, 1u);
                if (p < LBUF) lbuf[p] = key;
                else {                            // overflow fallback (not expected)
                    unsigned pos = atomicAdd(&cnt[n], 1u);
                    if (pos < CAP) cp[pos] = key;
                }
            }
        }
    }
    __syncthreads();
    // phase 4: one global reservation, coalesced flush
    const unsigned L = (lcnt_sh < LBUF) ? lcnt_sh : LBUF;
    if (tid == 0) gbase_sh = atomicAdd(&cnt[n], L);
    __syncthreads();
    const unsigned gb = gbase_sh;
    for (unsigned t = tid; t < L; t += 1024) {
        unsigned pos = gb + t;
        if (pos < CAP) cp[pos] = lbuf[t];
    }
}

// ---- K3: per-image bitonic sort (2048 if C<=2048, else 4096; desc) + decode ----
__global__ void __launch_bounds__(1024) k_sort_decode(
        const unsigned long long* __restrict__ cand,
        const unsigned* __restrict__ cnt,
        const float* __restrict__ deltas,
        float* __restrict__ topb,
        float* __restrict__ tops) {
    __shared__ unsigned long long sk[CAP];
    const int n = blockIdx.x, tid = threadIdx.x;
    const unsigned long long* cp = cand + (size_t)n * CAP;
    const int C = (int)cnt[n];
    const int NEL = (C <= 2048) ? 2048 : CAP;
    for (int t = tid; t < NEL; t += 1024)
        sk[t] = (t < C) ? cp[t] : 0ull;        // zero-fill pad (no memset needed)
    __syncthreads();
    for (int k = 2; k <= NEL; k <<= 1) {
        for (int j = k >> 1; j > 0; j >>= 1) {
            for (int p = tid; p < (NEL >> 1); p += 1024) {
                int t = ((p & ~(j - 1)) << 1) | (p & (j - 1));
                int ixj = t | j;
                unsigned long long a = sk[t], b = sk[ixj];
                bool up = (t & k) == 0;
                if (up ? (a < b) : (a > b)) { sk[t] = b; sk[ixj] = a; }
            }
            __syncthreads();
        }
    }
    // decode the top PRE entries (C >= PRE guaranteed by cutoff choice)
    const float* dp = deltas + (size_t)n * (NA * 4 * HW);
    for (int t = tid; t < PRE; t += 1024) {
        unsigned long long key = sk[t];
        unsigned sb = (unsigned)(key >> 32);
        unsigned j  = 0xFFFFFFFFu - (unsigned)(key & 0xFFFFFFFFull);
        float s = __uint_as_float(sb);
        int a  = (int)(j % NA), hw = (int)(j / NA);
        int gy = hw / GW, gx = hw % GW;
        int r  = a / 5, si = a % 5;
        // cell anchor, bit-exact vs reference f32 math
        float ratio = (r == 0) ? 0.5f : ((r == 1) ? 1.0f : 2.0f);
        float hr = __fsqrt_rn(ratio);
        float wr = __fdiv_rn(1.0f, hr);
        float scale = (float)(32 << si);
        float wsz = __fmul_rn(wr, scale);
        float hsz = __fmul_rn(hr, scale);
        float bx1 = rintf(__fmul_rn(-wsz, 0.5f));
        float by1 = rintf(__fmul_rn(-hsz, 0.5f));
        float bx2 = rintf(__fmul_rn(wsz, 0.5f));
        float by2 = rintf(__fmul_rn(hsz, 0.5f));
        float sx = (float)(gx * 16), sy = (float)(gy * 16);
        float ax1 = sx + bx1, ay1 = sy + by1, ax2 = sx + bx2, ay2 = sy + by2;
        float wa = __fsub_rn(ax2, ax1), ha = __fsub_rn(ay2, ay1);
        float cxa = __fadd_rn(ax1, __fmul_rn(0.5f, wa));
        float cya = __fadd_rn(ay1, __fmul_rn(0.5f, ha));
        int off = gy * GW + gx;
        float dx = dp[(a * 4 + 0) * HW + off];
        float dy = dp[(a * 4 + 1) * HW + off];
        float dw = fminf(dp[(a * 4 + 2) * HW + off], BBOX_CLIP_F);
        float dh = fminf(dp[(a * 4 + 3) * HW + off], BBOX_CLIP_F);
        float cx = __fadd_rn(__fmul_rn(dx, wa), cxa);
        float cy = __fadd_rn(__fmul_rn(dy, ha), cya);
        float bw = __fmul_rn(ref_exp_f32(dw), wa);
        float bh = __fmul_rn(ref_exp_f32(dh), ha);
        float hbw = __fmul_rn(0.5f, bw), hbh = __fmul_rn(0.5f, bh);
        float x1 = fminf(fmaxf(__fsub_rn(cx, hbw), 0.0f), IMGSZ);
        float y1 = fminf(fmaxf(__fsub_rn(cy, hbh), 0.0f), IMGSZ);
        float x2 = fminf(fmaxf(__fadd_rn(cx, hbw), 0.0f), IMGSZ);
        float y2 = fminf(fmaxf(__fadd_rn(cy, hbh), 0.0f), IMGSZ);
        float* tb = topb + ((size_t)n * PRE + t) * 4;
        tb[0] = x1; tb[1] = y1; tb[2] = x2; tb[3] = y2;
        bool valid = (__fsub_rn(x2, x1) >= 1e-3f) && (__fsub_rn(y2, y1) >= 1e-3f);
        tops[(size_t)n * PRE + t] = valid ? s : -1.0f;
    }
}

// ---- K4: 2000x2000 IoU suppression bitmask (bit j of row i: j>i && iou>0.7) ----
// chunks c < i>>6 are all-zero by j>i -> start there (stored 0), ~1.9x less work.
__global__ void k_iou(const float* __restrict__ topb,
                      unsigned long long* __restrict__ mask) {
    __shared__ float X1[PRE], Y1[PRE], X2[PRE], Y2[PRE];
    const int n = blockIdx.x, rowblk = blockIdx.y, tid = threadIdx.x;
    const float4* tb4 = (const float4*)(topb + (size_t)n * PRE * 4);
    for (int t = tid; t < PRE; t += 256) {
        float4 b = tb4[t];
        X1[t] = b.x; Y1[t] = b.y; X2[t] = b.z; Y2[t] = b.w;
    }
    __syncthreads();
    const int wave = tid >> 6, lane = tid & 63;
    for (int rr = 0; rr < 8; ++rr) {
        int i = rowblk * 32 + wave * 8 + rr;
        if (i >= PRE) break;
        float bi0 = X1[i], bi1 = Y1[i], bi2 = X2[i], bi3 = Y2[i];
        float ai = __fmul_rn(__fsub_rn(bi2, bi0), __fsub_rn(bi3, bi1));
        unsigned long long* mrow = mask + ((size_t)n * MROWS + i) * 32;
        unsigned long long mval = 0ull;     // lane c<32 collects chunk c
        const int c0 = i >> 6;
        for (int c = c0; c < 32; ++c) {
            int j = c * 64 + lane;
            bool bit = false;
            if (j < PRE && j > i) {
                float bj0 = X1[j], bj1 = Y1[j], bj2 = X2[j], bj3 = Y2[j];
                float aj = __fmul_rn(__fsub_rn(bj2, bj0), __fsub_rn(bj3, bj1));
                float ltx = fmaxf(bi0, bj0), lty = fmaxf(bi1, bj1);
                float rbx = fminf(bi2, bj2), rby = fminf(bi3, bj3);
                float ww = fmaxf(__fsub_rn(rbx, ltx), 0.0f);
                float hh = fmaxf(__fsub_rn(rby, lty), 0.0f);
                float inter = __fmul_rn(ww, hh);
                float denom = __fadd_rn(__fsub_rn(__fadd_rn(ai, aj), inter), 1e-6f);
                bit = __fdiv_rn(inter, denom) > 0.7f;
            }
            unsigned long long m = __ballot(bit);
            if (lane == c) mval = m;
        }
        if (lane < 32) mrow[lane] = mval;   // one coalesced 256B store per row
    }
}

// ---- K5: greedy NMS. Pure-scalar decision chain; rr from the staged LDS buffer
// (no per-group global loads); parallel kept-emission; DMA two groups ahead.
__global__ void __launch_bounds__(256) k_nms_out(
        const float* __restrict__ topb,
        const float* __restrict__ tops,
        const unsigned long long* __restrict__ mask,
        float* __restrict__ out) {
    __shared__ unsigned long long sbuf[2][2048];   // 2 x 16 KB staging (64 rows each)
    __shared__ float sval[2048];                   // scores (8 KB)
    __shared__ unsigned short kept[POST];
    __shared__ int cnt;
    const int n = blockIdx.x, tid = threadIdx.x;   // 256 threads; wave 0 does NMS
    const float* sp = tops + (size_t)n * PRE;
    if (tid < 64) {
        const int lane = tid;
        const unsigned long long* mb = mask + (size_t)n * MROWS * 32;
        // stage scores via DMA (reads 192 B past tops[n] slice: inside ws pad)
        #pragma unroll
        for (int k = 0; k < 8; ++k)
            gl_lds16((const char*)sp + k * 1024 + lane * 16, (char*)sval + k * 1024);
        WAIT_VM(0);
        unsigned long long vbit = 0ull;   // lane w<32: validity of rows [64w,64w+64)
        #pragma unroll
        for (int w = 0; w < 32; ++w) {
            int i = w * 64 + lane;
            bool v = (i < PRE) && (sval[i] > -0.5f);
            unsigned long long m = __ballot(v);
            if (lane == w) vbit = m;
        }
        // prologue: stage groups 0 and 1
        #pragma unroll
        for (int k = 0; k < 16; ++k)
            gl_lds16((const char*)mb + k * 1024 + lane * 16,
                     (char*)&sbuf[0][0] + k * 1024);
        #pragma unroll
        for (int k = 0; k < 16; ++k)
            gl_lds16((const char*)(mb + (size_t)64 * 32) + k * 1024 + lane * 16,
                     (char*)&sbuf[1][0] + k * 1024);

        unsigned long long remv = 0ull;   // lane l owns suppression chunk (l&31)
        int kc = 0;
        for (int g = 0; g < 32; ++g) {
            const int base = g * 64;
            WAIT_VM(16);                   // stage(g) done; stage(g+1) may fly
            const unsigned long long* sb = sbuf[g & 1];
            // row (base+lane)'s chunk g (bank-aliased read, once per group)
            unsigned long long rr = sb[(size_t)lane * 32 + g];
            unsigned long long cc = rl64(remv, g);
            unsigned long long vb = rl64(vbit, g);
            // pure scalar greedy chain (no POST check: surplus kept are harmless,
            // reference also computes full keep then takes first POST)
            unsigned long long todo = vb & ~cc;
            unsigned long long kb = 0ull;
            while (todo) {
                int jj = (int)__builtin_ctzll(todo);
                unsigned long long bit = 1ull << jj;
                kb |= bit;
                unsigned long long sup = rl64(rr, jj);
                todo &= ~(sup | bit);
            }
            // parallel emission: rank by popcount-below
            if (kb) {
                if ((kb >> lane) & 1ull) {
                    int rank = __popcll(kb & ((1ull << lane) - 1ull));
                    int pos = kc + rank;
                    if (pos < POST) kept[pos] = (unsigned short)(base + lane);
                }
                kc += __popcll(kb);
            }
            if (kc >= POST || g == 31) break;   // future groups irrelevant
            // fold kept rows' full masks into remv (off the decision chain)
            if (kb) {
                int h = lane >> 5, c = lane & 31;
                unsigned kbl = (unsigned)(h ? (kb >> 32) : kb);
                unsigned long long acc = 0ull;
                #pragma unroll
                for (int q = 0; q < 32; ++q) {
                    unsigned long long v = sb[(h * 32 + q) * 32 + c];
                    acc |= ((kbl >> q) & 1u) ? v : 0ull;
                }
                acc |= __shfl(acc, lane ^ 32);   // merge row-halves
                remv |= acc;
            }
            WAIT_LGKM0;                      // LDS reads done before DMA overwrites
            if (g + 2 < 32) {                // stage(g+2) into same-parity buffer
                const char* gb = (const char*)(mb + (size_t)(g + 2) * 64 * 32);
                char* lb = (char*)&sbuf[g & 1][0];
                #pragma unroll
                for (int k = 0; k < 16; ++k)
                    gl_lds16(gb + k * 1024 + lane * 16, lb + k * 1024);
            }
        }
        if (lane == 0) cnt = (kc < POST) ? kc : POST;
    }
    __syncthreads();
    const int kc = cnt;
    for (int rI = tid; rI < POST; rI += 256) {
        float o0 = 0.f, o1 = 0.f, o2 = 0.f, o3 = 0.f, o4 = 0.f;
        if (rI < kc) {
            int i = kept[rI];
            const float* tb = topb + ((size_t)n * PRE + i) * 4;
            o0 = tb[0]; o1 = tb[1]; o2 = tb[2]; o3 = tb[3]; o4 = sval[i];
        }
        float* op = out + ((size_t)n * POST + rI) * 5;
        op[0] = o0; op[1] = o1; op[2] = o2; op[3] = o3; op[4] = o4;
    }
}

extern "C" void kernel_launch(void* const* d_in, const int* in_sizes, int n_in,
                              void* d_out, int out_size, void* d_ws, size_t ws_size,
                              hipStream_t stream) {
    const float* obj    = (const float*)d_in[0];   // [8,15,100,100]
    const float* deltas = (const float*)d_in[1];   // [8,60,100,100]
    float* out = (float*)d_out;                    // [8,1000,5]
    char* ws = (char*)d_ws;

    unsigned*            cnt   = (unsigned*)(ws + WS_CNT);
    unsigned long long*  cand  = (unsigned long long*)(ws + WS_CAND);
    unsigned*            phist = (unsigned*)(ws + WS_PHIST);
    float*               topb  = (float*)(ws + WS_TOPB);
    float*               tops  = (float*)(ws + WS_TOPS);
    unsigned long long*  mask  = (unsigned long long*)(ws + WS_MASK);

    k_hist       <<<dim3(NIMG, NSLICE), 1024, 0, stream>>>(obj, phist, cnt);
    k_compact    <<<dim3(NIMG, NSLICE), 1024, 0, stream>>>(obj, phist, cand, cnt);
    k_sort_decode<<<NIMG, 1024, 0, stream>>>(cand, cnt, deltas, topb, tops);
    k_iou        <<<dim3(NIMG, 63), 256, 0, stream>>>(topb, mask);
    k_nms_out    <<<NIMG, 256, 0, stream>>>(topb, tops, mask, out);
}